// Round 6
// baseline (137.105 us; speedup 1.0000x reference)
//
#include <hip/hip_runtime.h>

// x:(8,32,32,64,64) f32 -> out:(8,32,48,96,96) f32
// variance=1: out = 2*log( trilinear( exp(x/2) ) ), identity grid, align_corners=True.
//
// Block = one (nc, zo). Two phases, ONE barrier:
//  Phase 1: G[y][x] = wz0*exp(in[z0,y,x]/2) + wz1*exp(in[z1,y,x]/2)  (LDS 17.4 KB, pad 68)
//  Phase 2: each thread emits 9 float4 quads of consecutive outputs:
//           per output read G[y0][x0..x1], G[y1][x0..x1] (merges to ds_read2_b32),
//           y-lerp + x-lerp + 2*log, nontemporal dwordx4 store (contiguous per wave).
// LDS 17408 B -> 8 blocks/CU (32-wave cap), vs 5 before.
constexpr int N = 8, C = 32, Din = 32, Hin = 64, Win = 64;
constexpr int Do = 48, Ho = 96, Wo = 96;

constexpr int BLOCK   = 256;
constexpr int NBLOCKS = N * C * Do;          // 12288 blocks, one per (nc, zo)
constexpr int GPAD    = 68;                  // 64+4: 16B-aligned rows, banks spread by 4/row

typedef float f32x4 __attribute__((ext_vector_type(4)));

__global__ __launch_bounds__(BLOCK)
void resample3d_var_kernel(const float* __restrict__ in, float* __restrict__ out) {
    __shared__ float G[Hin][GPAD];           // 17408 B

    const int tid = threadIdx.x;
    const int bid = blockIdx.x;
    const int zo  = bid % Do;
    const int nc  = bid / Do;

    // z weights (block-uniform)
    float fz  = (float)(zo * (Din - 1)) * (1.0f / (float)(Do - 1));
    int   z0  = (int)fz;
    float wz1 = fz - (float)z0;
    int   z1  = min(z0 + 1, Din - 1);
    float wz0 = 1.0f - wz1;

    const float* __restrict__ p0 = in + ((size_t)nc * Din + z0) * (Hin * Win);
    const float* __restrict__ p1 = in + ((size_t)nc * Din + z1) * (Hin * Win);

    constexpr float HALF_LOG2E = 0.7213475204444817f;   // 0.5*log2(e): exp(x/2)=exp2(x*K)

    // ---- Phase 1: stage G (4096 floats; float4 loads, 8 exps per iter) ----
    {
        const int sy = tid >> 4;             // 0..15
        const int sx = (tid & 15) << 2;      // 0,4,...,60
#pragma unroll
        for (int k = 0; k < 4; ++k) {
            int y = sy + k * 16;
            const float4 a = *reinterpret_cast<const float4*>(p0 + y * Win + sx);
            const float4 b = *reinterpret_cast<const float4*>(p1 + y * Win + sx);
            float4 g;
            g.x = wz0 * __builtin_amdgcn_exp2f(a.x * HALF_LOG2E) + wz1 * __builtin_amdgcn_exp2f(b.x * HALF_LOG2E);
            g.y = wz0 * __builtin_amdgcn_exp2f(a.y * HALF_LOG2E) + wz1 * __builtin_amdgcn_exp2f(b.y * HALF_LOG2E);
            g.z = wz0 * __builtin_amdgcn_exp2f(a.z * HALF_LOG2E) + wz1 * __builtin_amdgcn_exp2f(b.z * HALF_LOG2E);
            g.w = wz0 * __builtin_amdgcn_exp2f(a.w * HALF_LOG2E) + wz1 * __builtin_amdgcn_exp2f(b.w * HALF_LOG2E);
            *reinterpret_cast<float4*>(&G[y][sx]) = g;
        }
    }
    __syncthreads();

    // ---- Phase 2: 2304 quads, 9 per thread, fully coalesced nontemporal stores ----
    float* __restrict__ ob = out + ((size_t)nc * Do + zo) * (size_t)(Ho * Wo);
    constexpr float TWO_LN2 = 1.3862943611198906f;   // 2*logf(v) == TWO_LN2*log2f(v)

#pragma unroll 3
    for (int k = 0; k < 9; ++k) {
        int c   = k * BLOCK + tid;               // 0..2303
        int row = (c * 2731) >> 16;              // c/24, exact for c < 2304
        int q   = c - row * 24;

        float fy  = (float)(row * (Hin - 1)) * (1.0f / (float)(Ho - 1));
        int   y0  = (int)fy;
        float wy1 = fy - (float)y0;
        int   y1  = min(y0 + 1, Hin - 1);
        const float* __restrict__ g0 = &G[y0][0];
        const float* __restrict__ g1 = &G[y1][0];

        f32x4 o;
#pragma unroll
        for (int i = 0; i < 4; ++i) {
            int   xo  = q * 4 + i;
            float fx  = (float)(xo * (Win - 1)) * (1.0f / (float)(Wo - 1));
            int   x0  = (int)fx;
            float wx1 = fx - (float)x0;
            int   x1  = min(x0 + 1, Win - 1);
            float a0 = g0[x0], a1 = g0[x1];      // adjacent -> ds_read2_b32
            float b0 = g1[x0], b1 = g1[x1];
            float fa = a0 + wy1 * (b0 - a0);
            float fb = a1 + wy1 * (b1 - a1);
            float v  = fa + wx1 * (fb - fa);
            o[i] = TWO_LN2 * __log2f(v);
        }
        __builtin_nontemporal_store(o, reinterpret_cast<f32x4*>(ob + (size_t)c * 4));
    }
}

extern "C" void kernel_launch(void* const* d_in, const int* in_sizes, int n_in,
                              void* d_out, int out_size, void* d_ws, size_t ws_size,
                              hipStream_t stream) {
    const float* x = (const float*)d_in[0];
    float* out = (float*)d_out;
    resample3d_var_kernel<<<NBLOCKS, BLOCK, 0, stream>>>(x, out);
}